// Round 1
// 174.319 us; speedup vs baseline: 1.0171x; 1.0171x over previous
//
#include <hip/hip_runtime.h>

// GAE backward scan. B=4096 independent rows, T=2048 steps.
// R2 layout: one 512-thread block per row; thread j owns elements
// [4j, 4j+4) -> exactly ONE float4 per array per thread, so every
// global_load_dwordx4 is a fully-contiguous 1 KB wave transaction
// (R1's E=8 layout had 32 B lane stride = half-utilized lines per
// instruction). Register pressure drops from ~96 to <=48 VGPRs,
// lifting the occupancy cap from 5 waves/SIMD (62.5%) to 8 (100%),
// and the wave count doubles (32768) for latency hiding.
// Scan: per-thread serial (4 elems) -> per-wave __shfl_down suffix
// composition (6 steps) -> ONE __syncthreads to combine 8 wave-affines
// via LDS. Outputs stored nontemporal to keep inputs L3-resident.

constexpr float GAMMA = 0.99f;
constexpr float LMBDA = 0.95f;
constexpr int   T     = 2048;
constexpr int   TPB   = 512;
constexpr int   E     = T / TPB;        // 4 elements per thread
constexpr int   NW    = TPB / 64;       // 8 waves per block

typedef float f4 __attribute__((ext_vector_type(4)));

__global__ __launch_bounds__(TPB) void gae_kernel(
    const float* __restrict__ reward,
    const int*   __restrict__ term,
    const float* __restrict__ value,
    const float* __restrict__ next_value,
    float* __restrict__ adv_out,
    float* __restrict__ ret_out)
{
    const int j    = threadIdx.x;
    const int wave = j >> 6;
    const int lane = j & 63;
    const size_t base = (size_t)blockIdx.x * T + (size_t)j * E;

    // Fully-coalesced loads: one float4/int4 per array per thread.
    const float4 rv = ((const float4*)(reward     + base))[0];
    const int4   tv = ((const int4*  )(term       + base))[0];
    const float4 vv = ((const float4*)(value      + base))[0];
    const float4 nv = ((const float4*)(next_value + base))[0];

    const float r [E] = {rv.x, rv.y, rv.z, rv.w};
    const float nd[E] = {1.f - (float)tv.x, 1.f - (float)tv.y,
                         1.f - (float)tv.z, 1.f - (float)tv.w};
    const float v [E] = {vv.x, vv.y, vv.z, vv.w};
    const float nx[E] = {nv.x, nv.y, nv.z, nv.w};

    // Intra-thread backward scan, zero carry. loc[t] = local gae,
    // P[t] = product of c over [t..E-1].
    float loc[E], P[E];
    {
        float g = 0.f, p = 1.f;
        #pragma unroll
        for (int t = E - 1; t >= 0; --t) {
            const float c     = (GAMMA * LMBDA) * nd[t];
            const float delta = fmaf(GAMMA * nx[t], nd[t], r[t]) - v[t];
            g = fmaf(c, g, delta);
            p *= c;
            loc[t] = g;
            P[t]   = p;
        }
    }

    // Per-wave inclusive suffix-composition scan of (A, B) = (loc[0], P[0]).
    // (own o right)(x) = A1 + B1*(A2 + B2*x).
    float A = loc[0], Bc = P[0];
    #pragma unroll
    for (int off = 1; off < 64; off <<= 1) {
        const float a2 = __shfl_down(A,  off, 64);
        const float b2 = __shfl_down(Bc, off, 64);
        if (lane + off < 64) {
            A  = fmaf(Bc, a2, A);
            Bc *= b2;
        }
    }

    // Lane 0 holds the whole wave's affine. One barrier to share.
    __shared__ float sA[NW], sB[NW];
    if (lane == 0) { sA[wave] = A; sB[wave] = Bc; }

    // Exclusive suffix within the wave (from lane+1); lane 63 = identity.
    float eA = __shfl_down(A,  1, 64);
    float eB = __shfl_down(Bc, 1, 64);
    if (lane == 63) { eA = 0.f; eB = 1.f; }

    __syncthreads();

    // Carry entering this wave = composition of wave-affines to the right, at 0.
    float wcarry = 0.f;
    #pragma unroll
    for (int w = NW - 1; w > 0; --w) {
        if (w > wave) wcarry = fmaf(sB[w], wcarry, sA[w]);
    }

    // Carry entering this thread's chunk.
    const float gin = fmaf(eB, wcarry, eA);

    // adv[t] = loc[t] + P[t]*gin; ret = adv + v. Nontemporal stores:
    // outputs are never re-read, keep the L3 for the input arrays.
    f4 a4, q4;
    #pragma unroll
    for (int t = 0; t < E; ++t) {
        const float a = fmaf(P[t], gin, loc[t]);
        a4[t] = a;
        q4[t] = a + v[t];
    }
    __builtin_nontemporal_store(a4, (f4*)(adv_out + base));
    __builtin_nontemporal_store(q4, (f4*)(ret_out + base));
}

extern "C" void kernel_launch(void* const* d_in, const int* in_sizes, int n_in,
                              void* d_out, int out_size, void* d_ws, size_t ws_size,
                              hipStream_t stream) {
    const float* reward     = (const float*)d_in[0];
    const int*   term       = (const int*  )d_in[1];
    const float* value      = (const float*)d_in[2];
    const float* next_value = (const float*)d_in[3];

    const int BT = in_sizes[0];
    const int B  = BT / T;

    float* adv = (float*)d_out;
    float* ret = adv + BT;

    gae_kernel<<<B, TPB, 0, stream>>>(reward, term, value, next_value, adv, ret);
}